// Round 2
// baseline (2392.915 us; speedup 1.0000x reference)
//
#include <hip/hip_runtime.h>
#include <math.h>

static constexpr int B = 4, H = 160, W = 160;
static constexpr int HW = H * W;          // 25600
static constexpr int CHW = 64 * HW;       // 1638400
static constexpr int NELEM = B * CHW;     // 6553600

__device__ __forceinline__ float lrelu(float v) { return v >= 0.f ? v : 0.1f * v; }

// ---------------------------------------------------------------------------
// Weight transforms (run every call; tiny).
//   wt01[ci*64+o]          = w01[o*128+ci]          (8192)
//   wt_d[(k*64+ci)*64+o]   = dw[(o*64+ci)*9+k]      (36864)
//   arwT[cp*64+o]          = arw[o*192+cp]          (12288)
// ---------------------------------------------------------------------------
__global__ __launch_bounds__(256) void k_transform(
    const float* __restrict__ w01, const float* __restrict__ dw,
    const float* __restrict__ arw, float* __restrict__ wt01,
    float* __restrict__ wt_d, float* __restrict__ arwT) {
  int i = blockIdx.x * 256 + threadIdx.x;  // 0 .. 57343
  if (i < 8192) {
    int ci = i >> 6, o = i & 63;
    wt01[i] = w01[o * 128 + ci];
  } else if (i < 8192 + 36864) {
    int j = i - 8192;
    int k = j >> 12, r = j & 4095;
    int ci = r >> 6, o = r & 63;
    wt_d[j] = dw[(o * 64 + ci) * 9 + k];
  } else {
    int j = i - 45056;
    int cp = j >> 6, o = j & 63;
    arwT[j] = arw[o * 192 + cp];
  }
}

// ---------------------------------------------------------------------------
// Kernel A: 1x1 conv concat(aux,ref) 128->64 + bias + lrelu.
// Block = 64 positions; LDS-staged inputs; 16 out-ch per thread.
// grid: B*HW/64 = 1600
// ---------------------------------------------------------------------------
__global__ __launch_bounds__(256) void k_conv1x1_in(
    const float* __restrict__ aux, const float* __restrict__ ref,
    const float* __restrict__ wt01, const float* __restrict__ b01,
    float* __restrict__ out) {
  __shared__ float s[128 * 64];  // 32 KB  s[ci*64+p]
  int pos0 = blockIdx.x * 64;
  int b = pos0 / HW;
  int hw0 = pos0 - b * HW;
  int tid = threadIdx.x;
  for (int i = tid; i < 8192; i += 256) {
    int ci = i >> 6, p = i & 63;
    const float* src = (ci < 64) ? (aux + b * CHW + ci * HW)
                                 : (ref + b * CHW + (ci - 64) * HW);
    s[i] = src[hw0 + p];
  }
  __syncthreads();
  int p = tid & 63;
  int g = __builtin_amdgcn_readfirstlane(tid >> 6);  // wave-uniform out-group
  const float* wp = wt01 + g * 16;
  float acc[16];
#pragma unroll
  for (int j = 0; j < 16; ++j) acc[j] = 0.f;
#pragma unroll 4
  for (int ci = 0; ci < 128; ++ci) {
    float sv = s[ci * 64 + p];
    const float* wrow = wp + ci * 64;  // uniform, o-contiguous -> s_loads
#pragma unroll
    for (int j = 0; j < 16; ++j) acc[j] += sv * wrow[j];
  }
  const float* bb = b01 + g * 16;
  int obase = (b * 64 + g * 16) * HW + hw0 + p;
#pragma unroll
  for (int j = 0; j < 16; ++j) out[obase + j * HW] = lrelu(acc[j] + bb[j]);
}

// ---------------------------------------------------------------------------
// Kernel F: fused res-ASPP + merge + residual + offset head.
// Block = 16x8 spatial tile, 128 threads (1 pos/thread).
// 12 groups of 16 inter-channels; lrelu'd group streamed into macc[64];
// epilogue applies residual and computes the 18 offset channels directly.
// r1/r2/r3 and merged off_x are never materialized.
// grid: (10, 20, 4)
// ---------------------------------------------------------------------------
__global__ __launch_bounds__(128) void k_aspp_fused(
    const float* __restrict__ off0,
    const float* __restrict__ a1w, const float* __restrict__ a1b,
    const float* __restrict__ a2w, const float* __restrict__ a2b,
    const float* __restrict__ a3w, const float* __restrict__ a3b,
    const float* __restrict__ arwT, const float* __restrict__ arb,
    const float* __restrict__ w02, const float* __restrict__ b02,
    float* __restrict__ offs) {
  __shared__ float tile[8][384];  // 8 ci x (16 rows x 24 cols), 12 KB
  int tid = threadIdx.x;
  int tx = tid & 15, ty = tid >> 4;          // ty 0..7
  int bx = blockIdx.x, by = blockIdx.y, b = blockIdx.z;
  int h = by * 8 + ty, wv = bx * 16 + tx;
  float macc[64];
#pragma unroll
  for (int co = 0; co < 64; ++co) macc[co] = 0.f;

  for (int g = 0; g < 12; ++g) {
    int conv = g >> 2, sub = g & 3;
    int d = 1 << conv;  // 1, 2, 4
    const float* wb = (conv == 0 ? a1w : conv == 1 ? a2w : a3w) + (sub * 16) * 576;
    const float* bb = (conv == 0 ? a1b : conv == 1 ? a2b : a3b) + sub * 16;
    float rg[16];
#pragma unroll
    for (int j = 0; j < 16; ++j) rg[j] = 0.f;
    for (int cb = 0; cb < 64; cb += 8) {
      for (int i = tid; i < 3072; i += 128) {
        int c = i / 384, r = i - c * 384;
        int ly = r / 24, lx = r - ly * 24;
        int gy = by * 8 + ly - 4, gx = bx * 16 + lx - 4;
        float v = 0.f;
        if (gy >= 0 && gy < H && gx >= 0 && gx < W)
          v = off0[((b * 64 + cb + c) * H + gy) * W + gx];
        tile[c][r] = v;
      }
      __syncthreads();
      for (int c = 0; c < 8; ++c) {
        float s9[9];
#pragma unroll
        for (int ky = 0; ky < 3; ++ky)
#pragma unroll
          for (int kx = 0; kx < 3; ++kx)
            s9[ky * 3 + kx] =
                tile[c][(ty + 4 + (ky - 1) * d) * 24 + tx + 4 + (kx - 1) * d];
#pragma unroll
        for (int j = 0; j < 16; ++j) {
          const float* wj = wb + (j * 64 + cb + c) * 9;  // uniform s_loads
          float a = rg[j];
#pragma unroll
          for (int k = 0; k < 9; ++k) a += s9[k] * wj[k];
          rg[j] = a;
        }
      }
      __syncthreads();
    }
    // lrelu + stream into merged accumulators
#pragma unroll
    for (int j = 0; j < 16; ++j) {
      float r = lrelu(rg[j] + bb[j]);
      int cp = conv * 64 + sub * 16 + j;
      const float* arow = arwT + cp * 64;  // uniform, o-contiguous
#pragma unroll
      for (int co = 0; co < 64; ++co) macc[co] += arow[co] * r;
    }
  }
  // epilogue: residual + bias, then 1x1 offset head (64 -> 18)
  int pos = h * W + wv;
#pragma unroll
  for (int co = 0; co < 64; ++co)
    macc[co] += arb[co] + off0[(b * 64 + co) * HW + pos];
#pragma unroll
  for (int t = 0; t < 18; ++t) {
    const float* w2 = w02 + t * 64;
    float o = b02[t];
#pragma unroll
    for (int co = 0; co < 64; ++co) o += w2[co] * macc[co];
    offs[(b * 18 + t) * HW + pos] = o;
  }
}

// ---------------------------------------------------------------------------
// Kernel E: deformable 3x3 conv. Block = 64 positions, 256 threads.
// Per tap: sample s[ci][p] ONCE into LDS (each thread: 16 ci for its pos),
// then register matvec, 16 out-ch per thread, transposed weights (s_loads).
// grid: B*HW/64 = 1600
// ---------------------------------------------------------------------------
__global__ __launch_bounds__(256) void k_deform(
    const float* __restrict__ x, const float* __restrict__ offs,
    const float* __restrict__ wt_d, const float* __restrict__ db,
    float* __restrict__ out) {
  __shared__ float s[64 * 64];  // 16 KB  s[ci*64+p]
  int pos0 = blockIdx.x * 64;
  int b = pos0 / HW;
  int hw0 = pos0 - b * HW;
  int tid = threadIdx.x;
  int p = tid & 63;
  int g = __builtin_amdgcn_readfirstlane(tid >> 6);
  int hw = hw0 + p;
  int h = hw / W, wv = hw - h * W;
  const float* xb = x + b * CHW;
  const float* ob = offs + b * 18 * HW + hw;
  float acc[16];
#pragma unroll
  for (int j = 0; j < 16; ++j) acc[j] = 0.f;
  const float* wgp = wt_d + g * 16;

  for (int k = 0; k < 9; ++k) {
    int ky = k / 3, kx = k - ky * 3;
    float dy = ob[(2 * k) * HW];
    float dx = ob[(2 * k + 1) * HW];
    float py = dy + (float)(h - 1 + ky);
    float px = dx + (float)(wv - 1 + kx);
    float fy = floorf(py), fx = floorf(px);
    int iy0 = (int)fy, ix0 = (int)fx;
    float wy = py - fy, wx = px - fx;
    int iy1 = iy0 + 1, ix1 = ix0 + 1;
    float vy0 = (iy0 >= 0 && iy0 < H) ? 1.f : 0.f;
    float vy1 = (iy1 >= 0 && iy1 < H) ? 1.f : 0.f;
    float vx0 = (ix0 >= 0 && ix0 < W) ? 1.f : 0.f;
    float vx1 = (ix1 >= 0 && ix1 < W) ? 1.f : 0.f;
    int cy0 = min(max(iy0, 0), H - 1), cy1 = min(max(iy1, 0), H - 1);
    int cx0 = min(max(ix0, 0), W - 1), cx1 = min(max(ix1, 0), W - 1);
    float c00 = vy0 * vx0 * (1.f - wy) * (1.f - wx);
    float c01 = vy0 * vx1 * (1.f - wy) * wx;
    float c10 = vy1 * vx0 * wy * (1.f - wx);
    float c11 = vy1 * vx1 * wy * wx;
    int a00 = cy0 * W + cx0, a01 = cy0 * W + cx1;
    int a10 = cy1 * W + cx0, a11 = cy1 * W + cx1;
    int cib = g * 16;
#pragma unroll
    for (int i = 0; i < 16; ++i) {
      const float* xc = xb + (cib + i) * HW;
      s[(cib + i) * 64 + p] =
          c00 * xc[a00] + c01 * xc[a01] + c10 * xc[a10] + c11 * xc[a11];
    }
    __syncthreads();
#pragma unroll 4
    for (int ci = 0; ci < 64; ++ci) {
      float sv = s[ci * 64 + p];
      const float* wrow = wgp + (k * 64 + ci) * 64;  // uniform s_loads
#pragma unroll
      for (int j = 0; j < 16; ++j) acc[j] += sv * wrow[j];
    }
    __syncthreads();
  }
  int obase = (b * 64 + g * 16) * HW + hw;
#pragma unroll
  for (int j = 0; j < 16; ++j) out[obase + j * HW] = acc[j] + db[g * 16 + j];
}

// ---------------------------------------------------------------------------
extern "C" void kernel_launch(void* const* d_in, const int* in_sizes, int n_in,
                              void* d_out, int out_size, void* d_ws, size_t ws_size,
                              hipStream_t stream) {
  const float* aux = (const float*)d_in[0];
  const float* ref = (const float*)d_in[1];
  const float* w01 = (const float*)d_in[2];
  const float* b01 = (const float*)d_in[3];
  const float* a1w = (const float*)d_in[4];
  const float* a1b = (const float*)d_in[5];
  const float* a2w = (const float*)d_in[6];
  const float* a2b = (const float*)d_in[7];
  const float* a3w = (const float*)d_in[8];
  const float* a3b = (const float*)d_in[9];
  const float* arw = (const float*)d_in[10];
  const float* arb = (const float*)d_in[11];
  const float* w02 = (const float*)d_in[12];
  const float* b02 = (const float*)d_in[13];
  const float* dw  = (const float*)d_in[14];
  const float* db  = (const float*)d_in[15];
  float* out = (float*)d_out;

  float* off0 = (float*)d_ws;              // [B,64,H,W]
  float* offs = off0 + NELEM;              // [B,18,H,W]
  float* wt01 = offs + B * 18 * HW;        // 8192
  float* wt_d = wt01 + 8192;               // 36864
  float* arwT = wt_d + 36864;              // 12288

  k_transform<<<224, 256, 0, stream>>>(w01, dw, arw, wt01, wt_d, arwT);
  k_conv1x1_in<<<B * HW / 64, 256, 0, stream>>>(aux, ref, wt01, b01, off0);
  k_aspp_fused<<<dim3(10, 20, 4), 128, 0, stream>>>(
      off0, a1w, a1b, a2w, a2b, a3w, a3b, arwT, arb, w02, b02, offs);
  k_deform<<<B * HW / 64, 256, 0, stream>>>(aux, offs, wt_d, db, out);
}

// Round 3
// 1271.214 us; speedup vs baseline: 1.8824x; 1.8824x over previous
//
#include <hip/hip_runtime.h>
#include <math.h>

static constexpr int B = 4, H = 160, W = 160;
static constexpr int HW = H * W;          // 25600
static constexpr int CHW = 64 * HW;       // 1638400
static constexpr int NELEM = B * CHW;     // 6553600

__device__ __forceinline__ float lrelu(float v) { return v >= 0.f ? v : 0.1f * v; }

// ---------------------------------------------------------------------------
// Weight transforms (run every call; tiny).
//   wt01[ci*64+o]          = w01[o*128+ci]          (8192)
//   wt_d[(k*64+ci)*64+o]   = dw[(o*64+ci)*9+k]      (36864)
//   arwT[cp*64+o]          = arw[o*192+cp]          (12288)
// ---------------------------------------------------------------------------
__global__ __launch_bounds__(256) void k_transform(
    const float* __restrict__ w01, const float* __restrict__ dw,
    const float* __restrict__ arw, float* __restrict__ wt01,
    float* __restrict__ wt_d, float* __restrict__ arwT) {
  int i = blockIdx.x * 256 + threadIdx.x;  // 0 .. 57343
  if (i < 8192) {
    int ci = i >> 6, o = i & 63;
    wt01[i] = w01[o * 128 + ci];
  } else if (i < 8192 + 36864) {
    int j = i - 8192;
    int k = j >> 12, r = j & 4095;
    int ci = r >> 6, o = r & 63;
    wt_d[j] = dw[(o * 64 + ci) * 9 + k];
  } else {
    int j = i - 45056;
    int cp = j >> 6, o = j & 63;
    arwT[j] = arw[o * 192 + cp];
  }
}

// ---------------------------------------------------------------------------
// Kernel A: 1x1 conv concat(aux,ref) 128->64 + bias + lrelu.
// Block = 64 positions; LDS-staged inputs; 16 out-ch per thread.
// grid: B*HW/64 = 1600
// ---------------------------------------------------------------------------
__global__ __launch_bounds__(256) void k_conv1x1_in(
    const float* __restrict__ aux, const float* __restrict__ ref,
    const float* __restrict__ wt01, const float* __restrict__ b01,
    float* __restrict__ out) {
  __shared__ float s[128 * 64];  // 32 KB  s[ci*64+p]
  int pos0 = blockIdx.x * 64;
  int b = pos0 / HW;
  int hw0 = pos0 - b * HW;
  int tid = threadIdx.x;
  for (int i = tid; i < 8192; i += 256) {
    int ci = i >> 6, p = i & 63;
    const float* src = (ci < 64) ? (aux + b * CHW + ci * HW)
                                 : (ref + b * CHW + (ci - 64) * HW);
    s[i] = src[hw0 + p];
  }
  __syncthreads();
  int p = tid & 63;
  int g = __builtin_amdgcn_readfirstlane(tid >> 6);  // wave-uniform out-group
  const float* wp = wt01 + g * 16;
  float acc[16];
#pragma unroll
  for (int j = 0; j < 16; ++j) acc[j] = 0.f;
#pragma unroll 4
  for (int ci = 0; ci < 128; ++ci) {
    float sv = s[ci * 64 + p];
    const float* wrow = wp + ci * 64;  // uniform, o-contiguous -> s_loads
#pragma unroll
    for (int j = 0; j < 16; ++j) acc[j] += sv * wrow[j];
  }
  const float* bb = b01 + g * 16;
  int obase = (b * 64 + g * 16) * HW + hw0 + p;
#pragma unroll
  for (int j = 0; j < 16; ++j) out[obase + j * HW] = lrelu(acc[j] + bb[j]);
}

// ---------------------------------------------------------------------------
// Kernel B: all THREE dilated 3x3 convs in one pass (shared halo-4 staging).
// Block = 16x16 positions (256 thr); 16 out-ch per dilation per thread
// (acc[3][16] = 48 VGPR accumulators -> no spill).
// grid: (10, 10, B*4) ; blockIdx.z = b*4 + og
// ---------------------------------------------------------------------------
__global__ __launch_bounds__(256) void k_aspp3(
    const float* __restrict__ off0,
    const float* __restrict__ a1w, const float* __restrict__ a1b,
    const float* __restrict__ a2w, const float* __restrict__ a2b,
    const float* __restrict__ a3w, const float* __restrict__ a3b,
    float* __restrict__ r1, float* __restrict__ r2, float* __restrict__ r3) {
  __shared__ float tile[8 * 576];  // 8 ci x 24x24 halo tile, 18 KB
  int tid = threadIdx.x;
  int tx = tid & 15, ty = tid >> 4;
  int bx = blockIdx.x, by = blockIdx.y;
  int b = blockIdx.z >> 2, og = blockIdx.z & 3;
  float acc[3][16];
#pragma unroll
  for (int d = 0; d < 3; ++d)
#pragma unroll
    for (int j = 0; j < 16; ++j) acc[d][j] = 0.f;

  const float* src = off0 + b * CHW;
  for (int cb = 0; cb < 64; cb += 8) {
    for (int i = tid; i < 4608; i += 256) {
      int c = i / 576, r = i - c * 576;
      int ly = r / 24, lx = r - ly * 24;
      int gy = by * 16 + ly - 4, gx = bx * 16 + lx - 4;
      float v = 0.f;
      if (gy >= 0 && gy < H && gx >= 0 && gx < W)
        v = src[(cb + c) * HW + gy * W + gx];
      tile[i] = v;
    }
    __syncthreads();
    for (int c = 0; c < 8; ++c) {
      const float* tc = tile + c * 576;
      int ctr = (ty + 4) * 24 + tx + 4;
#pragma unroll
      for (int dsel = 0; dsel < 3; ++dsel) {
        const int d = 1 << dsel;
        float s9[9];
#pragma unroll
        for (int ky = 0; ky < 3; ++ky)
#pragma unroll
          for (int kx = 0; kx < 3; ++kx)
            s9[ky * 3 + kx] = tc[ctr + (ky - 1) * d * 24 + (kx - 1) * d];
        const float* wsel = (dsel == 0 ? a1w : dsel == 1 ? a2w : a3w);
#pragma unroll
        for (int j = 0; j < 16; ++j) {
          const float* wj = wsel + ((og * 16 + j) * 64 + cb + c) * 9;  // s_loads
          float a = acc[dsel][j];
#pragma unroll
          for (int k = 0; k < 9; ++k) a += s9[k] * wj[k];
          acc[dsel][j] = a;
        }
      }
    }
    __syncthreads();
  }
  int pos = (by * 16 + ty) * W + bx * 16 + tx;
  int obase = (b * 64 + og * 16) * HW + pos;
#pragma unroll
  for (int j = 0; j < 16; ++j) {
    r1[obase + j * HW] = lrelu(acc[0][j] + a1b[og * 16 + j]);
    r2[obase + j * HW] = lrelu(acc[1][j] + a2b[og * 16 + j]);
    r3[obase + j * HW] = lrelu(acc[2][j] + a3b[og * 16 + j]);
  }
}

// ---------------------------------------------------------------------------
// Kernel C: merge 192->64 (+bias+residual) then offset head 64->18 fused.
// Block = 64 positions, 256 thr. r1/r2/r3 staged to LDS (48 KB);
// merged values round-trip through the same LDS before the head.
// grid: B*HW/64 = 1600
// ---------------------------------------------------------------------------
__global__ __launch_bounds__(256) void k_merge_head(
    const float* __restrict__ r1, const float* __restrict__ r2,
    const float* __restrict__ r3, const float* __restrict__ off0,
    const float* __restrict__ arwT, const float* __restrict__ arb,
    const float* __restrict__ w02, const float* __restrict__ b02,
    float* __restrict__ offs) {
  __shared__ float s[192 * 64];  // 48 KB  s[cp*64+p]
  int pos0 = blockIdx.x * 64;
  int b = pos0 / HW;
  int hw0 = pos0 - b * HW;
  int tid = threadIdx.x;
  for (int i = tid; i < 4096; i += 256) {
    int c = i >> 6, p = i & 63;
    int gidx = (b * 64 + c) * HW + hw0 + p;
    s[i] = r1[gidx];
    s[4096 + i] = r2[gidx];
    s[8192 + i] = r3[gidx];
  }
  __syncthreads();
  int p = tid & 63;
  int g = __builtin_amdgcn_readfirstlane(tid >> 6);
  float macc[16];
#pragma unroll
  for (int j = 0; j < 16; ++j)
    macc[j] = arb[g * 16 + j] + off0[(b * 64 + g * 16 + j) * HW + hw0 + p];
#pragma unroll 4
  for (int cp = 0; cp < 192; ++cp) {
    float sv = s[cp * 64 + p];
    const float* arow = arwT + cp * 64 + g * 16;  // uniform s_loads
#pragma unroll
    for (int j = 0; j < 16; ++j) macc[j] += sv * arow[j];
  }
  __syncthreads();  // everyone done reading s
#pragma unroll
  for (int j = 0; j < 16; ++j) s[(g * 16 + j) * 64 + p] = macc[j];
  __syncthreads();
  // head: 18 out-ch x 64 pos = 1152 outputs; t is wave-uniform per iteration
  for (int i = tid; i < 1152; i += 256) {
    int t = i >> 6, pp = i & 63;
    const float* w2 = w02 + t * 64;  // uniform s_loads
    float o = b02[t];
#pragma unroll 8
    for (int co = 0; co < 64; ++co) o += s[co * 64 + pp] * w2[co];
    offs[(b * 18 + t) * HW + hw0 + pp] = o;
  }
}

// ---------------------------------------------------------------------------
// Kernel E: deformable 3x3 conv. Block = 64 positions, 256 threads.
// Per tap: sample s[ci][p] ONCE into LDS, then register matvec,
// 16 out-ch per thread, transposed weights (s_loads).
// grid: B*HW/64 = 1600
// ---------------------------------------------------------------------------
__global__ __launch_bounds__(256) void k_deform(
    const float* __restrict__ x, const float* __restrict__ offs,
    const float* __restrict__ wt_d, const float* __restrict__ db,
    float* __restrict__ out) {
  __shared__ float s[64 * 64];  // 16 KB  s[ci*64+p]
  int pos0 = blockIdx.x * 64;
  int b = pos0 / HW;
  int hw0 = pos0 - b * HW;
  int tid = threadIdx.x;
  int p = tid & 63;
  int g = __builtin_amdgcn_readfirstlane(tid >> 6);
  int hw = hw0 + p;
  int h = hw / W, wv = hw - h * W;
  const float* xb = x + b * CHW;
  const float* ob = offs + b * 18 * HW + hw;
  float acc[16];
#pragma unroll
  for (int j = 0; j < 16; ++j) acc[j] = 0.f;
  const float* wgp = wt_d + g * 16;

  for (int k = 0; k < 9; ++k) {
    int ky = k / 3, kx = k - ky * 3;
    float dy = ob[(2 * k) * HW];
    float dx = ob[(2 * k + 1) * HW];
    float py = dy + (float)(h - 1 + ky);
    float px = dx + (float)(wv - 1 + kx);
    float fy = floorf(py), fx = floorf(px);
    int iy0 = (int)fy, ix0 = (int)fx;
    float wy = py - fy, wx = px - fx;
    int iy1 = iy0 + 1, ix1 = ix0 + 1;
    float vy0 = (iy0 >= 0 && iy0 < H) ? 1.f : 0.f;
    float vy1 = (iy1 >= 0 && iy1 < H) ? 1.f : 0.f;
    float vx0 = (ix0 >= 0 && ix0 < W) ? 1.f : 0.f;
    float vx1 = (ix1 >= 0 && ix1 < W) ? 1.f : 0.f;
    int cy0 = min(max(iy0, 0), H - 1), cy1 = min(max(iy1, 0), H - 1);
    int cx0 = min(max(ix0, 0), W - 1), cx1 = min(max(ix1, 0), W - 1);
    float c00 = vy0 * vx0 * (1.f - wy) * (1.f - wx);
    float c01 = vy0 * vx1 * (1.f - wy) * wx;
    float c10 = vy1 * vx0 * wy * (1.f - wx);
    float c11 = vy1 * vx1 * wy * wx;
    int a00 = cy0 * W + cx0, a01 = cy0 * W + cx1;
    int a10 = cy1 * W + cx0, a11 = cy1 * W + cx1;
    int cib = g * 16;
#pragma unroll
    for (int i = 0; i < 16; ++i) {
      const float* xc = xb + (cib + i) * HW;
      s[(cib + i) * 64 + p] =
          c00 * xc[a00] + c01 * xc[a01] + c10 * xc[a10] + c11 * xc[a11];
    }
    __syncthreads();
#pragma unroll 4
    for (int ci = 0; ci < 64; ++ci) {
      float sv = s[ci * 64 + p];
      const float* wrow = wgp + (k * 64 + ci) * 64;  // uniform s_loads
#pragma unroll
      for (int j = 0; j < 16; ++j) acc[j] += sv * wrow[j];
    }
    __syncthreads();
  }
  int obase = (b * 64 + g * 16) * HW + hw;
#pragma unroll
  for (int j = 0; j < 16; ++j) out[obase + j * HW] = acc[j] + db[g * 16 + j];
}

// ---------------------------------------------------------------------------
extern "C" void kernel_launch(void* const* d_in, const int* in_sizes, int n_in,
                              void* d_out, int out_size, void* d_ws, size_t ws_size,
                              hipStream_t stream) {
  const float* aux = (const float*)d_in[0];
  const float* ref = (const float*)d_in[1];
  const float* w01 = (const float*)d_in[2];
  const float* b01 = (const float*)d_in[3];
  const float* a1w = (const float*)d_in[4];
  const float* a1b = (const float*)d_in[5];
  const float* a2w = (const float*)d_in[6];
  const float* a2b = (const float*)d_in[7];
  const float* a3w = (const float*)d_in[8];
  const float* a3b = (const float*)d_in[9];
  const float* arw = (const float*)d_in[10];
  const float* arb = (const float*)d_in[11];
  const float* w02 = (const float*)d_in[12];
  const float* b02 = (const float*)d_in[13];
  const float* dw  = (const float*)d_in[14];
  const float* db  = (const float*)d_in[15];
  float* out = (float*)d_out;

  float* off0 = (float*)d_ws;              // [B,64,H,W]
  float* r1   = off0 + NELEM;              // [B,64,H,W]
  float* r2   = r1 + NELEM;
  float* r3   = r2 + NELEM;
  float* offs = r3 + NELEM;                // [B,18,H,W]
  float* wt01 = offs + B * 18 * HW;        // 8192
  float* wt_d = wt01 + 8192;               // 36864
  float* arwT = wt_d + 36864;              // 12288

  k_transform<<<224, 256, 0, stream>>>(w01, dw, arw, wt01, wt_d, arwT);
  k_conv1x1_in<<<B * HW / 64, 256, 0, stream>>>(aux, ref, wt01, b01, off0);
  k_aspp3<<<dim3(10, 10, B * 4), 256, 0, stream>>>(
      off0, a1w, a1b, a2w, a2b, a3w, a3b, r1, r2, r3);
  k_merge_head<<<B * HW / 64, 256, 0, stream>>>(
      r1, r2, r3, off0, arwT, arb, w02, b02, offs);
  k_deform<<<B * HW / 64, 256, 0, stream>>>(aux, offs, wt_d, db, out);
}

// Round 4
// 516.097 us; speedup vs baseline: 4.6366x; 2.4631x over previous
//
#include <hip/hip_runtime.h>
#include <math.h>

static constexpr int B = 4, H = 160, W = 160;
static constexpr int HW = H * W;          // 25600
static constexpr int CHW = 64 * HW;       // 1638400
static constexpr int NELEM = B * CHW;     // 6553600

typedef short bf16x8 __attribute__((ext_vector_type(8)));
typedef float f32x4 __attribute__((ext_vector_type(4)));

__device__ __forceinline__ float lrelu(float v) { return v >= 0.f ? v : 0.1f * v; }

__device__ __forceinline__ unsigned short f2bf(float f) {
  unsigned u = __float_as_uint(f);
  return (unsigned short)((u + 0x7FFFu + ((u >> 16) & 1u)) >> 16);  // RNE
}

// ---------------------------------------------------------------------------
// Weight transforms (every call; tiny).
//   wt01[ci*64+o]        = w01[o*128+ci]                (8192 f32)
//   wt_d[(k*64+ci)*64+o] = dw[(o*64+ci)*9+k]            (36864 f32)
//   arwT[cp*64+o]        = arw[o*192+cp]                (12288 f32)
//   wb_bf[((dsel*9+k)*64+co)*64+ci] = bf16(aXw[(co*64+ci)*9+k])   (110592 bf16)
// ---------------------------------------------------------------------------
__global__ __launch_bounds__(256) void k_transform(
    const float* __restrict__ w01, const float* __restrict__ dw,
    const float* __restrict__ arw, const float* __restrict__ a1w,
    const float* __restrict__ a2w, const float* __restrict__ a3w,
    float* __restrict__ wt01, float* __restrict__ wt_d,
    float* __restrict__ arwT, unsigned short* __restrict__ wb_bf) {
  int i = blockIdx.x * 256 + threadIdx.x;  // 0 .. 167935
  if (i < 8192) {
    int ci = i >> 6, o = i & 63;
    wt01[i] = w01[o * 128 + ci];
  } else if (i < 8192 + 36864) {
    int j = i - 8192;
    int k = j >> 12, r = j & 4095;
    int ci = r >> 6, o = r & 63;
    wt_d[j] = dw[(o * 64 + ci) * 9 + k];
  } else if (i < 57344) {
    int j = i - 45056;
    int cp = j >> 6, o = j & 63;
    arwT[j] = arw[o * 192 + cp];
  } else if (i < 57344 + 110592) {
    int j = i - 57344;
    int ci = j & 63, co = (j >> 6) & 63;
    int kk = j >> 12;              // dsel*9 + k, 0..26
    int dsel = kk / 9; kk -= dsel * 9;
    const float* src = dsel == 0 ? a1w : dsel == 1 ? a2w : a3w;
    wb_bf[j] = f2bf(src[(co * 64 + ci) * 9 + kk]);
  }
}

// ---------------------------------------------------------------------------
// Kernel A: 1x1 conv concat(aux,ref) 128->64 + bias + lrelu.
// Writes fp32 channel-major off0 AND bf16 position-major off0_bf[pos][ci].
// grid: B*HW/64 = 1600, block 256
// ---------------------------------------------------------------------------
__global__ __launch_bounds__(256) void k_conv1x1_in(
    const float* __restrict__ aux, const float* __restrict__ ref,
    const float* __restrict__ wt01, const float* __restrict__ b01,
    float* __restrict__ out, unsigned short* __restrict__ out_bf) {
  __shared__ float s[128 * 64];  // 32 KB  s[ci*64+p]
  int pos0 = blockIdx.x * 64;
  int b = pos0 / HW;
  int hw0 = pos0 - b * HW;
  int tid = threadIdx.x;
  for (int i = tid; i < 8192; i += 256) {
    int ci = i >> 6, p = i & 63;
    const float* src = (ci < 64) ? (aux + b * CHW + ci * HW)
                                 : (ref + b * CHW + (ci - 64) * HW);
    s[i] = src[hw0 + p];
  }
  __syncthreads();
  int p = tid & 63;
  int g = __builtin_amdgcn_readfirstlane(tid >> 6);
  const float* wp = wt01 + g * 16;
  float acc[16];
#pragma unroll
  for (int j = 0; j < 16; ++j) acc[j] = 0.f;
#pragma unroll 4
  for (int ci = 0; ci < 128; ++ci) {
    float sv = s[ci * 64 + p];
    const float* wrow = wp + ci * 64;  // uniform, o-contiguous -> s_loads
#pragma unroll
    for (int j = 0; j < 16; ++j) acc[j] += sv * wrow[j];
  }
  const float* bb = b01 + g * 16;
  int obase = (b * 64 + g * 16) * HW + hw0 + p;
  unsigned short tb[16];
#pragma unroll
  for (int j = 0; j < 16; ++j) {
    float v = lrelu(acc[j] + bb[j]);
    out[obase + j * HW] = v;
    tb[j] = f2bf(v);
  }
  unsigned short* dst = out_bf + ((size_t)(b * HW + hw0 + p)) * 64 + g * 16;
  *(uint4*)dst = *(const uint4*)&tb[0];
  *(uint4*)(dst + 8) = *(const uint4*)&tb[8];
}

// ---------------------------------------------------------------------------
// Kernel B: MFMA fused tri-dilation ASPP conv (bf16 in, fp32 out).
// Block: 16x16 output tile, 4 waves; wave = 4 m-tiles (rows) x 4 n-tiles (64 co).
// K-loop: 2 ci-chunks x 9 taps; A from LDS tile [pix][ci32] (CIP=40, 16B-aligned),
// B (weights) from global, 16B/lane. Epilogue: LDS transpose -> channel-major r.
// grid: (10, 10, 12)  z = dsel*4 + b
// ---------------------------------------------------------------------------
__global__ __launch_bounds__(256) void k_aspp3_mfma(
    const unsigned short* __restrict__ off0_bf,
    const unsigned short* __restrict__ wb_bf,
    const float* __restrict__ a1b, const float* __restrict__ a2b,
    const float* __restrict__ a3b,
    float* __restrict__ r1, float* __restrict__ r2, float* __restrict__ r3) {
  __shared__ unsigned short sin[576 * 40];  // 46080 B; reused as float ep[256*33]
  int bx = blockIdx.x, by = blockIdx.y;
  int dsel = blockIdx.z >> 2, b = blockIdx.z & 3;
  int d = 1 << dsel;
  const float* bias = dsel == 0 ? a1b : dsel == 1 ? a2b : a3b;
  float* rout = dsel == 0 ? r1 : dsel == 1 ? r2 : r3;
  int tid = threadIdx.x;
  int lane = tid & 63, wid = tid >> 6;
  int m = lane & 15, q = lane >> 4;
  f32x4 acc[4][4] = {};
  const unsigned short* wbase = wb_bf + dsel * 9 * 4096;

  for (int ch = 0; ch < 2; ++ch) {
    __syncthreads();
    // stage 24x24 halo tile, 32 ci of this chunk, pos-major ci-contiguous
    for (int i = tid; i < 2304; i += 256) {
      int pix = i >> 2, sub = i & 3;
      int py = pix / 24, px = pix - py * 24;
      int gy = by * 16 + py - 4, gx = bx * 16 + px - 4;
      uint4 v = make_uint4(0u, 0u, 0u, 0u);
      if (gy >= 0 && gy < H && gx >= 0 && gx < W)
        v = *(const uint4*)(off0_bf +
                            ((size_t)(b * HW + gy * W + gx)) * 64 + ch * 32 + sub * 8);
      *(uint4*)(sin + pix * 40 + sub * 8) = v;
    }
    __syncthreads();
#pragma unroll
    for (int k = 0; k < 9; ++k) {
      int ky = k / 3, kx = k - ky * 3;
      bf16x8 bfrag[4];
#pragma unroll
      for (int t = 0; t < 4; ++t)
        bfrag[t] = *(const bf16x8*)(wbase + ((k * 64 + t * 16 + m) * 64) + ch * 32 + q * 8);
      bf16x8 afrag[4];
#pragma unroll
      for (int mt = 0; mt < 4; ++mt) {
        int row = 4 + wid * 4 + mt + (ky - 1) * d;
        int col = 4 + m + (kx - 1) * d;
        afrag[mt] = *(const bf16x8*)(sin + (row * 24 + col) * 40 + q * 8);
      }
#pragma unroll
      for (int mt = 0; mt < 4; ++mt)
#pragma unroll
        for (int t = 0; t < 4; ++t)
          acc[mt][t] = __builtin_amdgcn_mfma_f32_16x16x32_bf16(
              afrag[mt], bfrag[t], acc[mt][t], 0, 0, 0);
    }
  }

  // epilogue: transpose via LDS in two half-passes of 32 co each
  float* ep = (float*)sin;  // ep[pix*33 + c], c = co within half-pass
  for (int hp = 0; hp < 2; ++hp) {
    __syncthreads();
#pragma unroll
    for (int t2 = 0; t2 < 2; ++t2) {
      int t = hp * 2 + t2;
#pragma unroll
      for (int mt = 0; mt < 4; ++mt) {
        int prow = wid * 4 + mt;
#pragma unroll
        for (int r = 0; r < 4; ++r) {
          int pix = prow * 16 + q * 4 + r;
          ep[pix * 33 + t2 * 16 + m] = acc[mt][t][r];  // D: col=lane&15, row=q*4+r
        }
      }
    }
    __syncthreads();
    for (int it = 0; it < 32; ++it) {
      int c = it, pix = tid;  // c uniform per iter; conflict-free LDS reads
      int prow = pix >> 4, pcol = pix & 15;
      int co = hp * 32 + c;
      float v = ep[pix * 33 + c] + bias[co];
      rout[((size_t)(b * 64 + co)) * HW + (by * 16 + prow) * W + bx * 16 + pcol] =
          lrelu(v);
    }
  }
}

// ---------------------------------------------------------------------------
// Kernel C: merge 192->64 (+bias+residual) then offset head 64->18 fused.
// grid: B*HW/64 = 1600
// ---------------------------------------------------------------------------
__global__ __launch_bounds__(256) void k_merge_head(
    const float* __restrict__ r1, const float* __restrict__ r2,
    const float* __restrict__ r3, const float* __restrict__ off0,
    const float* __restrict__ arwT, const float* __restrict__ arb,
    const float* __restrict__ w02, const float* __restrict__ b02,
    float* __restrict__ offs) {
  __shared__ float s[192 * 64];  // 48 KB  s[cp*64+p]
  int pos0 = blockIdx.x * 64;
  int b = pos0 / HW;
  int hw0 = pos0 - b * HW;
  int tid = threadIdx.x;
  for (int i = tid; i < 4096; i += 256) {
    int c = i >> 6, p = i & 63;
    int gidx = (b * 64 + c) * HW + hw0 + p;
    s[i] = r1[gidx];
    s[4096 + i] = r2[gidx];
    s[8192 + i] = r3[gidx];
  }
  __syncthreads();
  int p = tid & 63;
  int g = __builtin_amdgcn_readfirstlane(tid >> 6);
  float macc[16];
#pragma unroll
  for (int j = 0; j < 16; ++j)
    macc[j] = arb[g * 16 + j] + off0[(b * 64 + g * 16 + j) * HW + hw0 + p];
#pragma unroll 4
  for (int cp = 0; cp < 192; ++cp) {
    float sv = s[cp * 64 + p];
    const float* arow = arwT + cp * 64 + g * 16;  // uniform s_loads
#pragma unroll
    for (int j = 0; j < 16; ++j) macc[j] += sv * arow[j];
  }
  __syncthreads();
#pragma unroll
  for (int j = 0; j < 16; ++j) s[(g * 16 + j) * 64 + p] = macc[j];
  __syncthreads();
  for (int i = tid; i < 1152; i += 256) {
    int t = i >> 6, pp = i & 63;
    const float* w2 = w02 + t * 64;
    float o = b02[t];
#pragma unroll 8
    for (int co = 0; co < 64; ++co) o += s[co * 64 + pp] * w2[co];
    offs[(b * 18 + t) * HW + hw0 + pp] = o;
  }
}

// ---------------------------------------------------------------------------
// Kernel E: deformable 3x3 conv. grid: B*HW/64 = 1600
// ---------------------------------------------------------------------------
__global__ __launch_bounds__(256) void k_deform(
    const float* __restrict__ x, const float* __restrict__ offs,
    const float* __restrict__ wt_d, const float* __restrict__ db,
    float* __restrict__ out) {
  __shared__ float s[64 * 64];  // 16 KB  s[ci*64+p]
  int pos0 = blockIdx.x * 64;
  int b = pos0 / HW;
  int hw0 = pos0 - b * HW;
  int tid = threadIdx.x;
  int p = tid & 63;
  int g = __builtin_amdgcn_readfirstlane(tid >> 6);
  int hw = hw0 + p;
  int h = hw / W, wv = hw - h * W;
  const float* xb = x + b * CHW;
  const float* ob = offs + b * 18 * HW + hw;
  float acc[16];
#pragma unroll
  for (int j = 0; j < 16; ++j) acc[j] = 0.f;
  const float* wgp = wt_d + g * 16;

  for (int k = 0; k < 9; ++k) {
    int ky = k / 3, kx = k - ky * 3;
    float dy = ob[(2 * k) * HW];
    float dx = ob[(2 * k + 1) * HW];
    float py = dy + (float)(h - 1 + ky);
    float px = dx + (float)(wv - 1 + kx);
    float fy = floorf(py), fx = floorf(px);
    int iy0 = (int)fy, ix0 = (int)fx;
    float wy = py - fy, wx = px - fx;
    int iy1 = iy0 + 1, ix1 = ix0 + 1;
    float vy0 = (iy0 >= 0 && iy0 < H) ? 1.f : 0.f;
    float vy1 = (iy1 >= 0 && iy1 < H) ? 1.f : 0.f;
    float vx0 = (ix0 >= 0 && ix0 < W) ? 1.f : 0.f;
    float vx1 = (ix1 >= 0 && ix1 < W) ? 1.f : 0.f;
    int cy0 = min(max(iy0, 0), H - 1), cy1 = min(max(iy1, 0), H - 1);
    int cx0 = min(max(ix0, 0), W - 1), cx1 = min(max(ix1, 0), W - 1);
    float c00 = vy0 * vx0 * (1.f - wy) * (1.f - wx);
    float c01 = vy0 * vx1 * (1.f - wy) * wx;
    float c10 = vy1 * vx0 * wy * (1.f - wx);
    float c11 = vy1 * vx1 * wy * wx;
    int a00 = cy0 * W + cx0, a01 = cy0 * W + cx1;
    int a10 = cy1 * W + cx0, a11 = cy1 * W + cx1;
    int cib = g * 16;
#pragma unroll
    for (int i = 0; i < 16; ++i) {
      const float* xc = xb + (cib + i) * HW;
      s[(cib + i) * 64 + p] =
          c00 * xc[a00] + c01 * xc[a01] + c10 * xc[a10] + c11 * xc[a11];
    }
    __syncthreads();
#pragma unroll 4
    for (int ci = 0; ci < 64; ++ci) {
      float sv = s[ci * 64 + p];
      const float* wrow = wgp + (k * 64 + ci) * 64;  // uniform s_loads
#pragma unroll
      for (int j = 0; j < 16; ++j) acc[j] += sv * wrow[j];
    }
    __syncthreads();
  }
  int obase = (b * 64 + g * 16) * HW + hw;
#pragma unroll
  for (int j = 0; j < 16; ++j) out[obase + j * HW] = acc[j] + db[g * 16 + j];
}

// ---------------------------------------------------------------------------
extern "C" void kernel_launch(void* const* d_in, const int* in_sizes, int n_in,
                              void* d_out, int out_size, void* d_ws, size_t ws_size,
                              hipStream_t stream) {
  const float* aux = (const float*)d_in[0];
  const float* ref = (const float*)d_in[1];
  const float* w01 = (const float*)d_in[2];
  const float* b01 = (const float*)d_in[3];
  const float* a1w = (const float*)d_in[4];
  const float* a1b = (const float*)d_in[5];
  const float* a2w = (const float*)d_in[6];
  const float* a2b = (const float*)d_in[7];
  const float* a3w = (const float*)d_in[8];
  const float* a3b = (const float*)d_in[9];
  const float* arw = (const float*)d_in[10];
  const float* arb = (const float*)d_in[11];
  const float* w02 = (const float*)d_in[12];
  const float* b02 = (const float*)d_in[13];
  const float* dw  = (const float*)d_in[14];
  const float* db  = (const float*)d_in[15];
  float* out = (float*)d_out;

  float* off0 = (float*)d_ws;              // [B,64,H,W] fp32
  float* r1   = off0 + NELEM;
  float* r2   = r1 + NELEM;
  float* r3   = r2 + NELEM;
  float* offs = r3 + NELEM;                // [B,18,H,W]
  float* wt01 = offs + B * 18 * HW;        // 8192
  float* wt_d = wt01 + 8192;               // 36864
  float* arwT = wt_d + 36864;              // 12288
  unsigned short* off0_bf = (unsigned short*)(arwT + 12288);  // [B,HW,64] bf16
  unsigned short* wb_bf = off0_bf + (size_t)NELEM;            // 110592 bf16

  k_transform<<<656, 256, 0, stream>>>(w01, dw, arw, a1w, a2w, a3w,
                                       wt01, wt_d, arwT, wb_bf);
  k_conv1x1_in<<<B * HW / 64, 256, 0, stream>>>(aux, ref, wt01, b01, off0,
                                                off0_bf);
  k_aspp3_mfma<<<dim3(10, 10, 12), 256, 0, stream>>>(
      off0_bf, wb_bf, a1b, a2b, a3b, r1, r2, r3);
  k_merge_head<<<B * HW / 64, 256, 0, stream>>>(
      r1, r2, r3, off0, arwT, arb, w02, b02, offs);
  k_deform<<<B * HW / 64, 256, 0, stream>>>(aux, offs, wt_d, db, out);
}

// Round 5
// 378.561 us; speedup vs baseline: 6.3211x; 1.3633x over previous
//
#include <hip/hip_runtime.h>
#include <math.h>

static constexpr int B = 4, H = 160, W = 160;
static constexpr int HW = H * W;          // 25600
static constexpr int CHW = 64 * HW;       // 1638400
static constexpr int NELEM = B * CHW;     // 6553600

typedef short bf16x8 __attribute__((ext_vector_type(8)));
typedef float f32x4 __attribute__((ext_vector_type(4)));

__device__ __forceinline__ float lrelu(float v) { return v >= 0.f ? v : 0.1f * v; }

__device__ __forceinline__ unsigned short f2bf(float f) {
  unsigned u = __float_as_uint(f);
  return (unsigned short)((u + 0x7FFFu + ((u >> 16) & 1u)) >> 16);  // RNE
}
__device__ __forceinline__ float bf2f(short u) {
  return __uint_as_float(((unsigned)(unsigned short)u) << 16);
}

// ---------------------------------------------------------------------------
// Weight transforms (every call; tiny).
//   wt01[ci*64+o]              = w01[o*128+ci]                  (8192 f32)
//   arwT[cp*64+o]              = arw[o*192+cp]                  (12288 f32)
//   wb_bf[((ds*9+k)*64+co)*64+ci] = bf16(aXw[(co*64+ci)*9+k])   (110592 bf16)
//   wd_bf[(k*64+co)*64+ci]     = bf16(dw[(co*64+ci)*9+k])       (36864 bf16)
// ---------------------------------------------------------------------------
__global__ __launch_bounds__(256) void k_transform(
    const float* __restrict__ w01, const float* __restrict__ dw,
    const float* __restrict__ arw, const float* __restrict__ a1w,
    const float* __restrict__ a2w, const float* __restrict__ a3w,
    float* __restrict__ wt01, float* __restrict__ arwT,
    unsigned short* __restrict__ wb_bf, unsigned short* __restrict__ wd_bf) {
  int i = blockIdx.x * 256 + threadIdx.x;  // 0 .. 167935
  if (i < 8192) {
    int ci = i >> 6, o = i & 63;
    wt01[i] = w01[o * 128 + ci];
  } else if (i < 20480) {
    int j = i - 8192;
    int cp = j >> 6, o = j & 63;
    arwT[j] = arw[o * 192 + cp];
  } else if (i < 131072) {
    int j = i - 20480;
    int ci = j & 63, co = (j >> 6) & 63;
    int kk = j >> 12;              // dsel*9 + k, 0..26
    int dsel = kk / 9; kk -= dsel * 9;
    const float* src = dsel == 0 ? a1w : dsel == 1 ? a2w : a3w;
    wb_bf[j] = f2bf(src[(co * 64 + ci) * 9 + kk]);
  } else if (i < 167936) {
    int j = i - 131072;
    int ci = j & 63, co = (j >> 6) & 63, k = j >> 12;  // k 0..8
    wd_bf[j] = f2bf(dw[(co * 64 + ci) * 9 + k]);
  }
}

// ---------------------------------------------------------------------------
// Kernel A: 1x1 conv concat(aux,ref) 128->64 + bias + lrelu.
// Writes fp32 channel-major off0 AND bf16 position-major off0_bf[pos][ci].
// grid: B*HW/64 = 1600
// ---------------------------------------------------------------------------
__global__ __launch_bounds__(256) void k_conv1x1_in(
    const float* __restrict__ aux, const float* __restrict__ ref,
    const float* __restrict__ wt01, const float* __restrict__ b01,
    float* __restrict__ out, unsigned short* __restrict__ out_bf) {
  __shared__ float s[128 * 64];  // 32 KB  s[ci*64+p]
  int pos0 = blockIdx.x * 64;
  int b = pos0 / HW;
  int hw0 = pos0 - b * HW;
  int tid = threadIdx.x;
  for (int i = tid; i < 8192; i += 256) {
    int ci = i >> 6, p = i & 63;
    const float* src = (ci < 64) ? (aux + b * CHW + ci * HW)
                                 : (ref + b * CHW + (ci - 64) * HW);
    s[i] = src[hw0 + p];
  }
  __syncthreads();
  int p = tid & 63;
  int g = __builtin_amdgcn_readfirstlane(tid >> 6);
  const float* wp = wt01 + g * 16;
  float acc[16];
#pragma unroll
  for (int j = 0; j < 16; ++j) acc[j] = 0.f;
#pragma unroll 4
  for (int ci = 0; ci < 128; ++ci) {
    float sv = s[ci * 64 + p];
    const float* wrow = wp + ci * 64;  // uniform, o-contiguous -> s_loads
#pragma unroll
    for (int j = 0; j < 16; ++j) acc[j] += sv * wrow[j];
  }
  const float* bb = b01 + g * 16;
  int obase = (b * 64 + g * 16) * HW + hw0 + p;
  unsigned short tb[16];
#pragma unroll
  for (int j = 0; j < 16; ++j) {
    float v = lrelu(acc[j] + bb[j]);
    out[obase + j * HW] = v;
    tb[j] = f2bf(v);
  }
  unsigned short* dst = out_bf + ((size_t)(b * HW + hw0 + p)) * 64 + g * 16;
  *(uint4*)dst = *(const uint4*)&tb[0];
  *(uint4*)(dst + 8) = *(const uint4*)&tb[8];
}

// ---------------------------------------------------------------------------
// Kernel B: MFMA fused tri-dilation ASPP conv (bf16 in, fp32 out).
// grid: (10, 10, 12)  z = dsel*4 + b
// ---------------------------------------------------------------------------
__global__ __launch_bounds__(256) void k_aspp3_mfma(
    const unsigned short* __restrict__ off0_bf,
    const unsigned short* __restrict__ wb_bf,
    const float* __restrict__ a1b, const float* __restrict__ a2b,
    const float* __restrict__ a3b,
    float* __restrict__ r1, float* __restrict__ r2, float* __restrict__ r3) {
  __shared__ unsigned short sin[576 * 40];  // 46080 B; reused as float ep[256*33]
  int bx = blockIdx.x, by = blockIdx.y;
  int dsel = blockIdx.z >> 2, b = blockIdx.z & 3;
  int d = 1 << dsel;
  const float* bias = dsel == 0 ? a1b : dsel == 1 ? a2b : a3b;
  float* rout = dsel == 0 ? r1 : dsel == 1 ? r2 : r3;
  int tid = threadIdx.x;
  int lane = tid & 63, wid = tid >> 6;
  int m = lane & 15, q = lane >> 4;
  f32x4 acc[4][4] = {};
  const unsigned short* wbase = wb_bf + dsel * 9 * 4096;

  for (int ch = 0; ch < 2; ++ch) {
    __syncthreads();
    for (int i = tid; i < 2304; i += 256) {
      int pix = i >> 2, sub = i & 3;
      int py = pix / 24, px = pix - py * 24;
      int gy = by * 16 + py - 4, gx = bx * 16 + px - 4;
      uint4 v = make_uint4(0u, 0u, 0u, 0u);
      if (gy >= 0 && gy < H && gx >= 0 && gx < W)
        v = *(const uint4*)(off0_bf +
                            ((size_t)(b * HW + gy * W + gx)) * 64 + ch * 32 + sub * 8);
      *(uint4*)(sin + pix * 40 + sub * 8) = v;
    }
    __syncthreads();
#pragma unroll
    for (int k = 0; k < 9; ++k) {
      int ky = k / 3, kx = k - ky * 3;
      bf16x8 bfrag[4];
#pragma unroll
      for (int t = 0; t < 4; ++t)
        bfrag[t] = *(const bf16x8*)(wbase + ((k * 64 + t * 16 + m) * 64) + ch * 32 + q * 8);
      bf16x8 afrag[4];
#pragma unroll
      for (int mt = 0; mt < 4; ++mt) {
        int row = 4 + wid * 4 + mt + (ky - 1) * d;
        int col = 4 + m + (kx - 1) * d;
        afrag[mt] = *(const bf16x8*)(sin + (row * 24 + col) * 40 + q * 8);
      }
#pragma unroll
      for (int mt = 0; mt < 4; ++mt)
#pragma unroll
        for (int t = 0; t < 4; ++t)
          acc[mt][t] = __builtin_amdgcn_mfma_f32_16x16x32_bf16(
              afrag[mt], bfrag[t], acc[mt][t], 0, 0, 0);
    }
  }

  float* ep = (float*)sin;  // ep[pix*33 + c]
  for (int hp = 0; hp < 2; ++hp) {
    __syncthreads();
#pragma unroll
    for (int t2 = 0; t2 < 2; ++t2) {
      int t = hp * 2 + t2;
#pragma unroll
      for (int mt = 0; mt < 4; ++mt) {
        int prow = wid * 4 + mt;
#pragma unroll
        for (int r = 0; r < 4; ++r) {
          int pix = prow * 16 + q * 4 + r;
          ep[pix * 33 + t2 * 16 + m] = acc[mt][t][r];  // D: col=lane&15, row=q*4+r
        }
      }
    }
    __syncthreads();
    for (int it = 0; it < 32; ++it) {
      int c = it, pix = tid;
      int prow = pix >> 4, pcol = pix & 15;
      int co = hp * 32 + c;
      float v = ep[pix * 33 + c] + bias[co];
      rout[((size_t)(b * 64 + co)) * HW + (by * 16 + prow) * W + bx * 16 + pcol] =
          lrelu(v);
    }
  }
}

// ---------------------------------------------------------------------------
// Kernel C: merge 192->64 (+bias+residual) then offset head 64->18 fused.
// grid: B*HW/64 = 1600
// ---------------------------------------------------------------------------
__global__ __launch_bounds__(256) void k_merge_head(
    const float* __restrict__ r1, const float* __restrict__ r2,
    const float* __restrict__ r3, const float* __restrict__ off0,
    const float* __restrict__ arwT, const float* __restrict__ arb,
    const float* __restrict__ w02, const float* __restrict__ b02,
    float* __restrict__ offs) {
  __shared__ float s[192 * 64];  // 48 KB  s[cp*64+p]
  int pos0 = blockIdx.x * 64;
  int b = pos0 / HW;
  int hw0 = pos0 - b * HW;
  int tid = threadIdx.x;
  for (int i = tid; i < 4096; i += 256) {
    int c = i >> 6, p = i & 63;
    int gidx = (b * 64 + c) * HW + hw0 + p;
    s[i] = r1[gidx];
    s[4096 + i] = r2[gidx];
    s[8192 + i] = r3[gidx];
  }
  __syncthreads();
  int p = tid & 63;
  int g = __builtin_amdgcn_readfirstlane(tid >> 6);
  float macc[16];
#pragma unroll
  for (int j = 0; j < 16; ++j)
    macc[j] = arb[g * 16 + j] + off0[(b * 64 + g * 16 + j) * HW + hw0 + p];
#pragma unroll 4
  for (int cp = 0; cp < 192; ++cp) {
    float sv = s[cp * 64 + p];
    const float* arow = arwT + cp * 64 + g * 16;  // uniform s_loads
#pragma unroll
    for (int j = 0; j < 16; ++j) macc[j] += sv * arow[j];
  }
  __syncthreads();
#pragma unroll
  for (int j = 0; j < 16; ++j) s[(g * 16 + j) * 64 + p] = macc[j];
  __syncthreads();
  for (int i = tid; i < 1152; i += 256) {
    int t = i >> 6, pp = i & 63;
    const float* w2 = w02 + t * 64;
    float o = b02[t];
#pragma unroll 8
    for (int co = 0; co < 64; ++co) o += s[co * 64 + pp] * w2[co];
    offs[(b * 18 + t) * HW + hw0 + pp] = o;
  }
}

// ---------------------------------------------------------------------------
// Kernel X: transpose aux -> position-major bf16 x_bf[b][hw][ci].
// grid: 1600 (runs after k_merge_head; reuses r1's workspace region)
// ---------------------------------------------------------------------------
__global__ __launch_bounds__(256) void k_xbf(
    const float* __restrict__ aux, unsigned short* __restrict__ x_bf) {
  __shared__ float s[64 * 64];
  int pos0 = blockIdx.x * 64;
  int b = pos0 / HW;
  int hw0 = pos0 - b * HW;
  int tid = threadIdx.x;
  for (int i = tid; i < 4096; i += 256) {
    int ci = i >> 6, p = i & 63;
    s[i] = aux[b * CHW + ci * HW + hw0 + p];
  }
  __syncthreads();
  int p = tid & 63, g = tid >> 6;
  unsigned short tb[16];
#pragma unroll
  for (int j = 0; j < 16; ++j) tb[j] = f2bf(s[(g * 16 + j) * 64 + p]);
  unsigned short* dst = x_bf + ((size_t)(b * HW + hw0 + p)) * 64 + g * 16;
  *(uint4*)dst = *(const uint4*)&tb[0];
  *(uint4*)(dst + 8) = *(const uint4*)&tb[8];
}

// ---------------------------------------------------------------------------
// Kernel E: deformable 3x3 conv, MFMA version.
// Block = 64 positions, 4 waves; wave = one 16-co n-tile x 4 m-tiles.
// Per tap: each thread samples 16 ci for its position (bf16 pos-major x),
// writes LDS [pos][ci] (stride 72, conflict-free), 1 barrier, 8 MFMAs/wave.
// XCD swizzle: contiguous 200-block slab per XCD for L2 halo reuse.
// grid: 1600
// ---------------------------------------------------------------------------
__global__ __launch_bounds__(256) void k_deform_mfma(
    const unsigned short* __restrict__ x_bf, const float* __restrict__ offs,
    const unsigned short* __restrict__ wd_bf, const float* __restrict__ db,
    float* __restrict__ out) {
  constexpr int SP = 72;                       // LDS row stride in bf16
  __shared__ unsigned short sb[2][64 * SP];    // 2 x 9216 B
  int blk = (blockIdx.x & 7) * 200 + (blockIdx.x >> 3);  // XCD slab swizzle
  int pos0 = blk * 64;
  int b = pos0 / HW;
  int hw0 = pos0 - b * HW;
  int tid = threadIdx.x;
  int lane = tid & 63, wid = tid >> 6;
  int m = lane & 15, q = lane >> 4;
  int p = lane;          // sampling position
  int cg = wid;          // sampling ci-group (16 ci)
  int hw = hw0 + p;
  int h = hw / W, wv = hw - h * W;
  const unsigned short* xb = x_bf + (size_t)b * HW * 64;
  const float* ob = offs + b * 18 * HW + hw;
  float offv[18];
#pragma unroll
  for (int j = 0; j < 18; ++j) offv[j] = ob[j * HW];
  f32x4 acc[4] = {};

#pragma unroll
  for (int k = 0; k < 9; ++k) {
    const int ky = k / 3, kx = k - ky * 3;
    float py = offv[2 * k] + (float)(h - 1 + ky);
    float px = offv[2 * k + 1] + (float)(wv - 1 + kx);
    float fy = floorf(py), fx = floorf(px);
    int iy0 = (int)fy, ix0 = (int)fx;
    float wy = py - fy, wx = px - fx;
    int iy1 = iy0 + 1, ix1 = ix0 + 1;
    float vy0 = (iy0 >= 0 && iy0 < H) ? 1.f : 0.f;
    float vy1 = (iy1 >= 0 && iy1 < H) ? 1.f : 0.f;
    float vx0 = (ix0 >= 0 && ix0 < W) ? 1.f : 0.f;
    float vx1 = (ix1 >= 0 && ix1 < W) ? 1.f : 0.f;
    int cy0 = min(max(iy0, 0), H - 1), cy1 = min(max(iy1, 0), H - 1);
    int cx0 = min(max(ix0, 0), W - 1), cx1 = min(max(ix1, 0), W - 1);
    float c00 = vy0 * vx0 * (1.f - wy) * (1.f - wx);
    float c01 = vy0 * vx1 * (1.f - wy) * wx;
    float c10 = vy1 * vx0 * wy * (1.f - wx);
    float c11 = vy1 * vx1 * wy * wx;
    const unsigned short* p00 = xb + (size_t)(cy0 * W + cx0) * 64 + cg * 16;
    const unsigned short* p01 = xb + (size_t)(cy0 * W + cx1) * 64 + cg * 16;
    const unsigned short* p10 = xb + (size_t)(cy1 * W + cx0) * 64 + cg * 16;
    const unsigned short* p11 = xb + (size_t)(cy1 * W + cx1) * 64 + cg * 16;
    unsigned short tb[16];
#pragma unroll
    for (int c2 = 0; c2 < 2; ++c2) {
      bf16x8 v00 = *(const bf16x8*)(p00 + c2 * 8);
      bf16x8 v01 = *(const bf16x8*)(p01 + c2 * 8);
      bf16x8 v10 = *(const bf16x8*)(p10 + c2 * 8);
      bf16x8 v11 = *(const bf16x8*)(p11 + c2 * 8);
#pragma unroll
      for (int j = 0; j < 8; ++j) {
        float sv = c00 * bf2f(v00[j]) + c01 * bf2f(v01[j]) +
                   c10 * bf2f(v10[j]) + c11 * bf2f(v11[j]);
        tb[c2 * 8 + j] = f2bf(sv);
      }
    }
    unsigned short* wr = &sb[k & 1][p * SP + cg * 16];
    *(uint4*)wr = *(const uint4*)&tb[0];
    *(uint4*)(wr + 8) = *(const uint4*)&tb[8];
    __syncthreads();
    const unsigned short* rb = &sb[k & 1][0];
#pragma unroll
    for (int kc = 0; kc < 2; ++kc) {
      bf16x8 bfrag =
          *(const bf16x8*)(wd_bf + (k * 64 + wid * 16 + m) * 64 + kc * 32 + q * 8);
#pragma unroll
      for (int mt = 0; mt < 4; ++mt) {
        bf16x8 afrag = *(const bf16x8*)(rb + (mt * 16 + m) * SP + kc * 32 + q * 8);
        acc[mt] = __builtin_amdgcn_mfma_f32_16x16x32_bf16(afrag, bfrag, acc[mt],
                                                          0, 0, 0);
      }
    }
  }
  int co = wid * 16 + m;
  float bias = db[co];
  size_t orow = (size_t)(b * 64 + co) * HW + hw0;
#pragma unroll
  for (int mt = 0; mt < 4; ++mt)
#pragma unroll
    for (int r = 0; r < 4; ++r)
      out[orow + mt * 16 + q * 4 + r] = acc[mt][r] + bias;  // D: col=co, row=pos
}

// ---------------------------------------------------------------------------
extern "C" void kernel_launch(void* const* d_in, const int* in_sizes, int n_in,
                              void* d_out, int out_size, void* d_ws, size_t ws_size,
                              hipStream_t stream) {
  const float* aux = (const float*)d_in[0];
  const float* ref = (const float*)d_in[1];
  const float* w01 = (const float*)d_in[2];
  const float* b01 = (const float*)d_in[3];
  const float* a1w = (const float*)d_in[4];
  const float* a1b = (const float*)d_in[5];
  const float* a2w = (const float*)d_in[6];
  const float* a2b = (const float*)d_in[7];
  const float* a3w = (const float*)d_in[8];
  const float* a3b = (const float*)d_in[9];
  const float* arw = (const float*)d_in[10];
  const float* arb = (const float*)d_in[11];
  const float* w02 = (const float*)d_in[12];
  const float* b02 = (const float*)d_in[13];
  const float* dw  = (const float*)d_in[14];
  const float* db  = (const float*)d_in[15];
  float* out = (float*)d_out;

  float* off0 = (float*)d_ws;              // [B,64,H,W] fp32
  float* r1   = off0 + NELEM;
  float* r2   = r1 + NELEM;
  float* r3   = r2 + NELEM;
  float* offs = r3 + NELEM;                // [B,18,H,W]
  float* wt01 = offs + B * 18 * HW;        // 8192
  float* arwT = wt01 + 8192;               // 12288
  unsigned short* off0_bf = (unsigned short*)(arwT + 12288);  // [B,HW,64] bf16
  unsigned short* wb_bf = off0_bf + (size_t)NELEM;            // 110592 bf16
  unsigned short* wd_bf = wb_bf + 110592;                     // 36864 bf16
  unsigned short* x_bf = (unsigned short*)r1;  // reuse r1 after merge_head

  k_transform<<<656, 256, 0, stream>>>(w01, dw, arw, a1w, a2w, a3w,
                                       wt01, arwT, wb_bf, wd_bf);
  k_conv1x1_in<<<B * HW / 64, 256, 0, stream>>>(aux, ref, wt01, b01, off0,
                                                off0_bf);
  k_aspp3_mfma<<<dim3(10, 10, 12), 256, 0, stream>>>(
      off0_bf, wb_bf, a1b, a2b, a3b, r1, r2, r3);
  k_merge_head<<<B * HW / 64, 256, 0, stream>>>(
      r1, r2, r3, off0, arwT, arb, w02, b02, offs);
  k_xbf<<<B * HW / 64, 256, 0, stream>>>(aux, x_bf);
  k_deform_mfma<<<B * HW / 64, 256, 0, stream>>>(x_bf, offs, wd_bf, db, out);
}

// Round 6
// 333.254 us; speedup vs baseline: 7.1805x; 1.1360x over previous
//
#include <hip/hip_runtime.h>
#include <math.h>

static constexpr int B = 4, H = 160, W = 160;
static constexpr int HW = H * W;          // 25600
static constexpr int CHW = 64 * HW;       // 1638400
static constexpr int NELEM = B * CHW;     // 6553600

typedef short bf16x8 __attribute__((ext_vector_type(8)));
typedef float f32x4 __attribute__((ext_vector_type(4)));

__device__ __forceinline__ float lrelu(float v) { return v >= 0.f ? v : 0.1f * v; }

__device__ __forceinline__ unsigned short f2bf(float f) {
  unsigned u = __float_as_uint(f);
  return (unsigned short)((u + 0x7FFFu + ((u >> 16) & 1u)) >> 16);  // RNE
}
__device__ __forceinline__ float bf2f(short u) {
  return __uint_as_float(((unsigned)(unsigned short)u) << 16);
}

// ---------------------------------------------------------------------------
// Weight transforms (every call; tiny).
//   wt01[ci*64+o]                  = w01[o*128+ci]              (8192 f32)
//   wb_bf[((ds*9+k)*64+co)*64+ci]  = bf16(aXw[(co*64+ci)*9+k])  (110592 bf16)
//   wd_bf[(k*64+co)*64+ci]         = bf16(dw[(co*64+ci)*9+k])   (36864 bf16)
//   arw_bf[o*192+cp]               = bf16(arw[o*192+cp])        (12288 bf16)
// ---------------------------------------------------------------------------
__global__ __launch_bounds__(256) void k_transform(
    const float* __restrict__ w01, const float* __restrict__ dw,
    const float* __restrict__ arw, const float* __restrict__ a1w,
    const float* __restrict__ a2w, const float* __restrict__ a3w,
    float* __restrict__ wt01, unsigned short* __restrict__ wb_bf,
    unsigned short* __restrict__ wd_bf, unsigned short* __restrict__ arw_bf) {
  int i = blockIdx.x * 256 + threadIdx.x;  // 0 .. 167935
  if (i < 8192) {
    int ci = i >> 6, o = i & 63;
    wt01[i] = w01[o * 128 + ci];
  } else if (i < 118784) {
    int j = i - 8192;
    int ci = j & 63, co = (j >> 6) & 63;
    int kk = j >> 12;              // dsel*9 + k, 0..26
    int dsel = kk / 9; kk -= dsel * 9;
    const float* src = dsel == 0 ? a1w : dsel == 1 ? a2w : a3w;
    wb_bf[j] = f2bf(src[(co * 64 + ci) * 9 + kk]);
  } else if (i < 155648) {
    int j = i - 118784;
    int ci = j & 63, co = (j >> 6) & 63, k = j >> 12;  // k 0..8
    wd_bf[j] = f2bf(dw[(co * 64 + ci) * 9 + k]);
  } else if (i < 167936) {
    int j = i - 155648;
    arw_bf[j] = f2bf(arw[j]);  // already [o][cp]
  }
}

// ---------------------------------------------------------------------------
// Kernel A: 1x1 conv concat(aux,ref) 128->64 + bias + lrelu.
// Emits fp32 channel-major off0, bf16 pos-major off0_bf[pos][ci], AND
// bf16 pos-major x_bf[pos][ci] (aux transpose, from the same LDS staging).
// grid: B*HW/64 = 1600
// ---------------------------------------------------------------------------
__global__ __launch_bounds__(256) void k_conv1x1_in(
    const float* __restrict__ aux, const float* __restrict__ ref,
    const float* __restrict__ wt01, const float* __restrict__ b01,
    float* __restrict__ out, unsigned short* __restrict__ out_bf,
    unsigned short* __restrict__ x_bf) {
  __shared__ float s[128 * 64];  // 32 KB  s[ci*64+p]
  int pos0 = blockIdx.x * 64;
  int b = pos0 / HW;
  int hw0 = pos0 - b * HW;
  int tid = threadIdx.x;
  for (int i = tid; i < 8192; i += 256) {
    int ci = i >> 6, p = i & 63;
    const float* src = (ci < 64) ? (aux + b * CHW + ci * HW)
                                 : (ref + b * CHW + (ci - 64) * HW);
    s[i] = src[hw0 + p];
  }
  __syncthreads();
  int p = tid & 63;
  int g = __builtin_amdgcn_readfirstlane(tid >> 6);
  const float* wp = wt01 + g * 16;
  float acc[16];
#pragma unroll
  for (int j = 0; j < 16; ++j) acc[j] = 0.f;
#pragma unroll 4
  for (int ci = 0; ci < 128; ++ci) {
    float sv = s[ci * 64 + p];
    const float* wrow = wp + ci * 64;  // uniform, o-contiguous -> s_loads
#pragma unroll
    for (int j = 0; j < 16; ++j) acc[j] += sv * wrow[j];
  }
  const float* bb = b01 + g * 16;
  int obase = (b * 64 + g * 16) * HW + hw0 + p;
  unsigned short tb[16];
#pragma unroll
  for (int j = 0; j < 16; ++j) {
    float v = lrelu(acc[j] + bb[j]);
    out[obase + j * HW] = v;
    tb[j] = f2bf(v);
  }
  unsigned short* dst = out_bf + ((size_t)(b * HW + hw0 + p)) * 64 + g * 16;
  *(uint4*)dst = *(const uint4*)&tb[0];
  *(uint4*)(dst + 8) = *(const uint4*)&tb[8];
  // x_bf: aux transpose from the staged LDS (rows 0..63 are aux)
  unsigned short xb[16];
#pragma unroll
  for (int j = 0; j < 16; ++j) xb[j] = f2bf(s[(g * 16 + j) * 64 + p]);
  unsigned short* xdst = x_bf + ((size_t)(b * HW + hw0 + p)) * 64 + g * 16;
  *(uint4*)xdst = *(const uint4*)&xb[0];
  *(uint4*)(xdst + 8) = *(const uint4*)&xb[8];
}

// ---------------------------------------------------------------------------
// Kernel B: MFMA fused tri-dilation ASPP conv (bf16 in, bf16 pos-major out).
// Output: r_bf[(b*HW+pos)*192 + dsel*64 + co] = lrelu(conv + bias)
// grid: (10, 10, 12)  z = dsel*4 + b
// ---------------------------------------------------------------------------
__global__ __launch_bounds__(256) void k_aspp3_mfma(
    const unsigned short* __restrict__ off0_bf,
    const unsigned short* __restrict__ wb_bf,
    const float* __restrict__ a1b, const float* __restrict__ a2b,
    const float* __restrict__ a3b, unsigned short* __restrict__ r_bf) {
  __shared__ unsigned short sin[576 * 40];  // 46080 B; reused as bf16 ep[256*72]
  int bx = blockIdx.x, by = blockIdx.y;
  int dsel = blockIdx.z >> 2, b = blockIdx.z & 3;
  int d = 1 << dsel;
  const float* bias = dsel == 0 ? a1b : dsel == 1 ? a2b : a3b;
  int tid = threadIdx.x;
  int lane = tid & 63, wid = tid >> 6;
  int m = lane & 15, q = lane >> 4;
  f32x4 acc[4][4] = {};
  const unsigned short* wbase = wb_bf + dsel * 9 * 4096;

  for (int ch = 0; ch < 2; ++ch) {
    __syncthreads();
    for (int i = tid; i < 2304; i += 256) {
      int pix = i >> 2, sub = i & 3;
      int py = pix / 24, px = pix - py * 24;
      int gy = by * 16 + py - 4, gx = bx * 16 + px - 4;
      uint4 v = make_uint4(0u, 0u, 0u, 0u);
      if (gy >= 0 && gy < H && gx >= 0 && gx < W)
        v = *(const uint4*)(off0_bf +
                            ((size_t)(b * HW + gy * W + gx)) * 64 + ch * 32 + sub * 8);
      *(uint4*)(sin + pix * 40 + sub * 8) = v;
    }
    __syncthreads();
#pragma unroll
    for (int k = 0; k < 9; ++k) {
      int ky = k / 3, kx = k - ky * 3;
      bf16x8 bfrag[4];
#pragma unroll
      for (int t = 0; t < 4; ++t)
        bfrag[t] = *(const bf16x8*)(wbase + ((k * 64 + t * 16 + m) * 64) + ch * 32 + q * 8);
      bf16x8 afrag[4];
#pragma unroll
      for (int mt = 0; mt < 4; ++mt) {
        int row = 4 + wid * 4 + mt + (ky - 1) * d;
        int col = 4 + m + (kx - 1) * d;
        afrag[mt] = *(const bf16x8*)(sin + (row * 24 + col) * 40 + q * 8);
      }
#pragma unroll
      for (int mt = 0; mt < 4; ++mt)
#pragma unroll
        for (int t = 0; t < 4; ++t)
          acc[mt][t] = __builtin_amdgcn_mfma_f32_16x16x32_bf16(
              afrag[mt], bfrag[t], acc[mt][t], 0, 0, 0);
    }
  }

  // epilogue: bias + lrelu, pack bf16 via LDS, 128B-contiguous global stores
  unsigned short* epb = sin;  // reuse; ep[pix*72 + co]
  __syncthreads();
#pragma unroll
  for (int t = 0; t < 4; ++t) {
    float bi = bias[t * 16 + m];
#pragma unroll
    for (int mt = 0; mt < 4; ++mt) {
      int prow = wid * 4 + mt;
#pragma unroll
      for (int r = 0; r < 4; ++r) {
        int pix = prow * 16 + q * 4 + r;  // D: col=lane&15, row=q*4+r
        epb[pix * 72 + t * 16 + m] = f2bf(lrelu(acc[mt][t][r] + bi));
      }
    }
  }
  __syncthreads();
  {
    int pix = tid;
    int prow = pix >> 4, pcol = pix & 15;
    unsigned short* dst =
        r_bf + ((size_t)(b * HW + (by * 16 + prow) * W + bx * 16 + pcol)) * 192 +
        dsel * 64;
    const unsigned short* src = epb + pix * 72;
#pragma unroll
    for (int c = 0; c < 8; ++c)
      *(uint4*)(dst + c * 8) = *(const uint4*)(src + c * 8);
  }
}

// ---------------------------------------------------------------------------
// Kernel C: MFMA merge 192->64 (+bias+residual) then offset head 64->18.
// Block = 64 positions; A = r_bf staged to LDS (stride 200, 2-way=free);
// B = arw_bf (already [co][cp]); M=64,N=64,K=192 -> 24 MFMAs.
// Head reads merged fp32 from LDS ep[pos*65+co] (conflict-free).
// grid: B*HW/64 = 1600
// ---------------------------------------------------------------------------
__global__ __launch_bounds__(256) void k_merge_head_mfma(
    const unsigned short* __restrict__ r_bf, const float* __restrict__ off0,
    const unsigned short* __restrict__ arw_bf, const float* __restrict__ arb,
    const float* __restrict__ w02, const float* __restrict__ b02,
    float* __restrict__ offs) {
  __shared__ unsigned short sa[64 * 200];  // 25600 B; reused as float ep[64*65]
  int pos0 = blockIdx.x * 64;
  int b = pos0 / HW;
  int hw0 = pos0 - b * HW;
  int tid = threadIdx.x;
  const unsigned short* gsrc = r_bf + (size_t)(b * HW + hw0) * 192;
  for (int i = tid; i < 1536; i += 256) {
    int pos = i / 24, c8 = i - pos * 24;
    *(uint4*)(sa + pos * 200 + c8 * 8) = *(const uint4*)(gsrc + i * 8);
  }
  __syncthreads();
  int lane = tid & 63, wid = tid >> 6;
  int m = lane & 15, q = lane >> 4;
  f32x4 acc[4] = {};
#pragma unroll
  for (int kc = 0; kc < 6; ++kc) {
    bf16x8 bfrag = *(const bf16x8*)(arw_bf + (wid * 16 + m) * 192 + kc * 32 + q * 8);
#pragma unroll
    for (int mt = 0; mt < 4; ++mt) {
      bf16x8 afrag = *(const bf16x8*)(sa + (mt * 16 + m) * 200 + kc * 32 + q * 8);
      acc[mt] = __builtin_amdgcn_mfma_f32_16x16x32_bf16(afrag, bfrag, acc[mt],
                                                        0, 0, 0);
    }
  }
  __syncthreads();  // all afrag reads done before overwriting sa
  float* ep = (float*)sa;  // ep[pos*65 + co]
  int co = wid * 16 + m;
  float bi = arb[co];
  const float* resrow = off0 + (size_t)(b * 64 + co) * HW + hw0;
#pragma unroll
  for (int mt = 0; mt < 4; ++mt)
#pragma unroll
    for (int r = 0; r < 4; ++r) {
      int pos = mt * 16 + q * 4 + r;  // D: col=co, row=pos
      ep[pos * 65 + co] = acc[mt][r] + bi + resrow[pos];
    }
  __syncthreads();
  for (int i = tid; i < 1152; i += 256) {
    int t = i >> 6, p = i & 63;
    const float* w2 = w02 + t * 64;  // t wave-uniform -> s_loads
    float o = b02[t];
#pragma unroll 8
    for (int c = 0; c < 64; ++c) o += ep[p * 65 + c] * w2[c];
    offs[(b * 18 + t) * HW + hw0 + p] = o;
  }
}

// ---------------------------------------------------------------------------
// Kernel E: deformable 3x3 conv, MFMA version (unchanged from R5).
// grid: 1600
// ---------------------------------------------------------------------------
__global__ __launch_bounds__(256) void k_deform_mfma(
    const unsigned short* __restrict__ x_bf, const float* __restrict__ offs,
    const unsigned short* __restrict__ wd_bf, const float* __restrict__ db,
    float* __restrict__ out) {
  constexpr int SP = 72;                       // LDS row stride in bf16
  __shared__ unsigned short sb[2][64 * SP];    // 2 x 9216 B
  int blk = (blockIdx.x & 7) * 200 + (blockIdx.x >> 3);  // XCD slab swizzle
  int pos0 = blk * 64;
  int b = pos0 / HW;
  int hw0 = pos0 - b * HW;
  int tid = threadIdx.x;
  int lane = tid & 63, wid = tid >> 6;
  int m = lane & 15, q = lane >> 4;
  int p = lane;          // sampling position
  int cg = wid;          // sampling ci-group (16 ci)
  int hw = hw0 + p;
  int h = hw / W, wv = hw - h * W;
  const unsigned short* xb = x_bf + (size_t)b * HW * 64;
  const float* ob = offs + b * 18 * HW + hw;
  float offv[18];
#pragma unroll
  for (int j = 0; j < 18; ++j) offv[j] = ob[j * HW];
  f32x4 acc[4] = {};

#pragma unroll
  for (int k = 0; k < 9; ++k) {
    const int ky = k / 3, kx = k - ky * 3;
    float py = offv[2 * k] + (float)(h - 1 + ky);
    float px = offv[2 * k + 1] + (float)(wv - 1 + kx);
    float fy = floorf(py), fx = floorf(px);
    int iy0 = (int)fy, ix0 = (int)fx;
    float wy = py - fy, wx = px - fx;
    int iy1 = iy0 + 1, ix1 = ix0 + 1;
    float vy0 = (iy0 >= 0 && iy0 < H) ? 1.f : 0.f;
    float vy1 = (iy1 >= 0 && iy1 < H) ? 1.f : 0.f;
    float vx0 = (ix0 >= 0 && ix0 < W) ? 1.f : 0.f;
    float vx1 = (ix1 >= 0 && ix1 < W) ? 1.f : 0.f;
    int cy0 = min(max(iy0, 0), H - 1), cy1 = min(max(iy1, 0), H - 1);
    int cx0 = min(max(ix0, 0), W - 1), cx1 = min(max(ix1, 0), W - 1);
    float c00 = vy0 * vx0 * (1.f - wy) * (1.f - wx);
    float c01 = vy0 * vx1 * (1.f - wy) * wx;
    float c10 = vy1 * vx0 * wy * (1.f - wx);
    float c11 = vy1 * vx1 * wy * wx;
    const unsigned short* p00 = xb + (size_t)(cy0 * W + cx0) * 64 + cg * 16;
    const unsigned short* p01 = xb + (size_t)(cy0 * W + cx1) * 64 + cg * 16;
    const unsigned short* p10 = xb + (size_t)(cy1 * W + cx0) * 64 + cg * 16;
    const unsigned short* p11 = xb + (size_t)(cy1 * W + cx1) * 64 + cg * 16;
    unsigned short tb[16];
#pragma unroll
    for (int c2 = 0; c2 < 2; ++c2) {
      bf16x8 v00 = *(const bf16x8*)(p00 + c2 * 8);
      bf16x8 v01 = *(const bf16x8*)(p01 + c2 * 8);
      bf16x8 v10 = *(const bf16x8*)(p10 + c2 * 8);
      bf16x8 v11 = *(const bf16x8*)(p11 + c2 * 8);
#pragma unroll
      for (int j = 0; j < 8; ++j) {
        float sv = c00 * bf2f(v00[j]) + c01 * bf2f(v01[j]) +
                   c10 * bf2f(v10[j]) + c11 * bf2f(v11[j]);
        tb[c2 * 8 + j] = f2bf(sv);
      }
    }
    unsigned short* wr = &sb[k & 1][p * SP + cg * 16];
    *(uint4*)wr = *(const uint4*)&tb[0];
    *(uint4*)(wr + 8) = *(const uint4*)&tb[8];
    __syncthreads();
    const unsigned short* rb = &sb[k & 1][0];
#pragma unroll
    for (int kc = 0; kc < 2; ++kc) {
      bf16x8 bfrag =
          *(const bf16x8*)(wd_bf + (k * 64 + wid * 16 + m) * 64 + kc * 32 + q * 8);
#pragma unroll
      for (int mt = 0; mt < 4; ++mt) {
        bf16x8 afrag = *(const bf16x8*)(rb + (mt * 16 + m) * SP + kc * 32 + q * 8);
        acc[mt] = __builtin_amdgcn_mfma_f32_16x16x32_bf16(afrag, bfrag, acc[mt],
                                                          0, 0, 0);
      }
    }
  }
  int co = wid * 16 + m;
  float bias = db[co];
  size_t orow = (size_t)(b * 64 + co) * HW + hw0;
#pragma unroll
  for (int mt = 0; mt < 4; ++mt)
#pragma unroll
    for (int r = 0; r < 4; ++r)
      out[orow + mt * 16 + q * 4 + r] = acc[mt][r] + bias;  // D: col=co, row=pos
}

// ---------------------------------------------------------------------------
extern "C" void kernel_launch(void* const* d_in, const int* in_sizes, int n_in,
                              void* d_out, int out_size, void* d_ws, size_t ws_size,
                              hipStream_t stream) {
  const float* aux = (const float*)d_in[0];
  const float* ref = (const float*)d_in[1];
  const float* w01 = (const float*)d_in[2];
  const float* b01 = (const float*)d_in[3];
  const float* a1w = (const float*)d_in[4];
  const float* a1b = (const float*)d_in[5];
  const float* a2w = (const float*)d_in[6];
  const float* a2b = (const float*)d_in[7];
  const float* a3w = (const float*)d_in[8];
  const float* a3b = (const float*)d_in[9];
  const float* arw = (const float*)d_in[10];
  const float* arb = (const float*)d_in[11];
  const float* w02 = (const float*)d_in[12];
  const float* b02 = (const float*)d_in[13];
  const float* dw  = (const float*)d_in[14];
  const float* db  = (const float*)d_in[15];
  float* out = (float*)d_out;

  float* off0 = (float*)d_ws;                        // [B,64,H,W] fp32
  float* offs = off0 + NELEM;                        // [B,18,H,W] fp32
  float* wt01 = offs + B * 18 * HW;                  // 8192 f32
  unsigned short* off0_bf = (unsigned short*)(wt01 + 8192);  // [B,HW,64] bf16
  unsigned short* x_bf   = off0_bf + (size_t)NELEM;          // [B,HW,64] bf16
  unsigned short* wb_bf  = x_bf + (size_t)NELEM;             // 110592 bf16
  unsigned short* wd_bf  = wb_bf + 110592;                   // 36864 bf16
  unsigned short* arw_bf = wd_bf + 36864;                    // 12288 bf16
  unsigned short* r_bf   = arw_bf + 12288;           // [B,HW,192] bf16

  k_transform<<<656, 256, 0, stream>>>(w01, dw, arw, a1w, a2w, a3w,
                                       wt01, wb_bf, wd_bf, arw_bf);
  k_conv1x1_in<<<B * HW / 64, 256, 0, stream>>>(aux, ref, wt01, b01, off0,
                                                off0_bf, x_bf);
  k_aspp3_mfma<<<dim3(10, 10, 12), 256, 0, stream>>>(
      off0_bf, wb_bf, a1b, a2b, a3b, r_bf);
  k_merge_head_mfma<<<B * HW / 64, 256, 0, stream>>>(
      r_bf, off0, arw_bf, arb, w02, b02, offs);
  k_deform_mfma<<<B * HW / 64, 256, 0, stream>>>(x_bf, offs, wd_bf, db, out);
}